// Round 1
// baseline (367.510 us; speedup 1.0000x reference)
//
#include <hip/hip_runtime.h>

// LIF neuron layer forward:
//   v_t = BETA * v_{t-1} * (1 - s_{t-1}) + i_t   (hard reset)
//   s_t = (v_t >= 1.0) ? 1 : 0
// Outputs (flat, concatenated): spikes (B,T,H), membrane (B,T,H), v_final (B,H)
// B=16, T=1024, H=2048, all fp32.
//
// Parallelization: one thread per (b,h) sequence (serial in T), 32768 threads.
// block=64 -> 512 blocks -> 2 waves/CU over all 256 CUs.
// Memory-bound: ~403 MB traffic -> ~64 us floor at 6.3 TB/s.

constexpr int B_ = 16;
constexpr int T_ = 1024;
constexpr int H_ = 2048;
constexpr float BETA = 0.904837f;
constexpr int U = 16;  // prefetch depth (loads in flight per thread)

__global__ __launch_bounds__(64) void lif_fwd_kernel(
    const float* __restrict__ in,   // (B,T,H)
    const float* __restrict__ v0,   // (B,H)
    float* __restrict__ sp,         // (B,T,H)
    float* __restrict__ mem,        // (B,T,H)
    float* __restrict__ vf)         // (B,H)
{
    const int idx = blockIdx.x * 64 + threadIdx.x;   // b*H + h, < 32768
    const int b = idx >> 11;                         // / H_
    const int h = idx & (H_ - 1);                    // % H_
    const size_t base = (size_t)b * T_ * H_ + (size_t)h;
    const float* __restrict__ ip = in + base;

    float v = v0[idx];
    float s = 0.0f;

    // Prime the prefetch pipeline: loads for t = 0..U-1.
    float cur[U];
#pragma unroll
    for (int j = 0; j < U; ++j) cur[j] = ip[(size_t)j * H_];

    int t0 = 0;
    for (; t0 < T_ - U; t0 += U) {
        // Issue next chunk's loads before consuming this chunk -> U loads in
        // flight across the dependent-recurrence compute below.
        float nxt[U];
#pragma unroll
        for (int j = 0; j < U; ++j) nxt[j] = ip[(size_t)(t0 + U + j) * H_];

#pragma unroll
        for (int j = 0; j < U; ++j) {
            // s in {0,1}: (1-s) multiply is exact, so FMA contraction is
            // bit-identical to the numpy two-step reference.
            v = BETA * v * (1.0f - s) + cur[j];
            s = (v >= 1.0f) ? 1.0f : 0.0f;
            const size_t o = base + (size_t)(t0 + j) * H_;
            sp[o] = s;
            mem[o] = v;
        }

#pragma unroll
        for (int j = 0; j < U; ++j) cur[j] = nxt[j];
    }

    // Last chunk (no further prefetch).
#pragma unroll
    for (int j = 0; j < U; ++j) {
        v = BETA * v * (1.0f - s) + cur[j];
        s = (v >= 1.0f) ? 1.0f : 0.0f;
        const size_t o = base + (size_t)(t0 + j) * H_;
        sp[o] = s;
        mem[o] = v;
    }

    vf[idx] = v;
}

extern "C" void kernel_launch(void* const* d_in, const int* in_sizes, int n_in,
                              void* d_out, int out_size, void* d_ws, size_t ws_size,
                              hipStream_t stream) {
    const float* in = (const float*)d_in[0];   // (B,T,H) = 33554432 elems
    const float* v0 = (const float*)d_in[1];   // (B,H)   = 32768 elems

    float* out = (float*)d_out;
    const size_t n_bth = (size_t)B_ * T_ * H_;       // 33554432
    float* sp  = out;                                 // spikes
    float* mem = out + n_bth;                         // membrane
    float* vf  = out + 2 * n_bth;                     // v_final

    const int threads = B_ * H_;                      // 32768
    const int block = 64;
    const int grid = threads / block;                 // 512
    lif_fwd_kernel<<<grid, block, 0, stream>>>(in, v0, sp, mem, vf);
}